// Round 4
// baseline (174.604 us; speedup 1.0000x reference)
//
#include <hip/hip_runtime.h>
#include <math.h>

#define NB 8
#define MSEG 16
#define PPIX (640*640)
#define PV4 (PPIX/4)        // 102400 int4/float4 groups per batch
#define GRIDX 100           // 100 blocks * 1024 groups each = 102400 exactly
#define DELTA_AGG 0.5f
#define DELTA_DIS 3.0f

// workspace float layout
#define OFF_CNT_K 0
#define OFF_CNT_T (NB*MSEG)            // 128
#define OFF_G     (2*NB*MSEG)          // 256 (N*M*4 floats; Gsum then finalized G in place)
#define OFF_LSUM  (6*NB*MSEG)          // 768
#define WS_FLOATS (7*NB*MSEG)          // 896

// ---------------- pass 1: segment sums by kern + histograms ----------------
// Fire-and-forget ds_add_f32 into per-thread-pair-private LDS columns:
// s_acc[arr][bin][col], col = tid>>1. No compare-loops, no RMW chains.
// arr: 0..3 = channel sums (kern), 4 = cnt_k, 5 = cnt_t.
__global__ __launch_bounds__(256) void pass1_kernel(
    const float* __restrict__ preds, const int* __restrict__ targets,
    float* __restrict__ ws) {
  const int n = blockIdx.y;
  const int tid = threadIdx.x;
  const int col = tid >> 1;

  const float4* __restrict__ c0 = (const float4*)(preds + ((size_t)n*6 + 2)*PPIX);
  const float4* __restrict__ c1 = (const float4*)(preds + ((size_t)n*6 + 3)*PPIX);
  const float4* __restrict__ c2 = (const float4*)(preds + ((size_t)n*6 + 4)*PPIX);
  const float4* __restrict__ c3 = (const float4*)(preds + ((size_t)n*6 + 5)*PPIX);
  const int4*  __restrict__ textv = (const int4*)(targets + (size_t)n*2*PPIX);
  const int4*  __restrict__ kernv = (const int4*)(targets + ((size_t)n*2 + 1)*PPIX);

  __shared__ float s_acc[6][MSEG][128];   // 48 KB
  {
    float4* f4 = (float4*)&s_acc[0][0][0];
#pragma unroll
    for (int i = 0; i < 12; ++i) f4[tid + i*256] = make_float4(0.f, 0.f, 0.f, 0.f);
  }
  __syncthreads();

#define PIX1(K, T, A0, A1, A2, A3) do {          \
    int k_ = (K), t_ = (T);                      \
    atomicAdd(&s_acc[0][k_][col], (A0));         \
    atomicAdd(&s_acc[1][k_][col], (A1));         \
    atomicAdd(&s_acc[2][k_][col], (A2));         \
    atomicAdd(&s_acc[3][k_][col], (A3));         \
    atomicAdd(&s_acc[4][k_][col], 1.0f);         \
    atomicAdd(&s_acc[5][t_][col], 1.0f);         \
  } while (0)

  const int base = blockIdx.x*1024 + tid;        // contiguous 1024-group chunk
#pragma unroll
  for (int it = 0; it < 4; ++it) {
    int p = base + it*256;
    int4 kk = kernv[p];
    int4 tt = textv[p];
    float4 a = c0[p], b = c1[p], c = c2[p], d = c3[p];
    PIX1(kk.x, tt.x, a.x, b.x, c.x, d.x);
    PIX1(kk.y, tt.y, a.y, b.y, c.y, d.y);
    PIX1(kk.z, tt.z, a.z, b.z, c.z, d.z);
    PIX1(kk.w, tt.w, a.w, b.w, c.w, d.w);
  }
#undef PIX1
  __syncthreads();

  // block reduce: 96 (arr,bin) pairs, 128 cols each
  if (tid < 96) {
    const int arr = tid >> 4, bin = tid & 15;
    const float4* row = (const float4*)&s_acc[arr][bin][0];
    float s = 0.f;
#pragma unroll
    for (int i = 0; i < 32; ++i) {
      float4 v = row[i];
      s += (v.x + v.y) + (v.z + v.w);
    }
    if (arr < 4)       atomicAdd(&ws[OFF_G + n*64 + bin*4 + arr], s);
    else if (arr == 4) atomicAdd(&ws[OFF_CNT_K + n*MSEG + bin], s);
    else               atomicAdd(&ws[OFF_CNT_T + n*MSEG + bin], s);
  }
}

// ------------- finalize G + discrimination loss (one block/batch) -------------
__global__ __launch_bounds__(256) void finalize_dis_kernel(
    float* __restrict__ ws, float* __restrict__ out) {
  const int n = blockIdx.x;
  const int tid = threadIdx.x;
  float* cnt_k = ws + OFF_CNT_K + n*MSEG;
  float* cnt_t = ws + OFF_CNT_T + n*MSEG;
  float* G     = ws + OFF_G     + (size_t)n*MSEG*4;

  __shared__ float s_G[MSEG][4];
  __shared__ int   s_valid[MSEG];
  __shared__ int   s_nv;
  __shared__ float red[256];

  if (tid < MSEG*4) {
    int m = tid >> 2;
    float g = G[tid] / fmaxf(cnt_k[m], 1.0f);
    s_G[m][tid & 3] = g;
    G[tid] = g;  // finalized G for pass 2
  }
  if (tid < MSEG)
    s_valid[tid] = (tid >= 1) && (cnt_k[tid] > 0.f) && (cnt_t[tid] > 0.f);
  __syncthreads();
  if (tid == 0) { int nv = 0; for (int m = 0; m < MSEG; m++) nv += s_valid[m]; s_nv = nv; }

  float lp = 0.f;
  {
    int i = tid >> 4, j = tid & 15;
    if (i != j && s_valid[i] && s_valid[j]) {
      float dx = s_G[i][0] - s_G[j][0];
      float dy = s_G[i][1] - s_G[j][1];
      float dz = s_G[i][2] - s_G[j][2];
      float dw = s_G[i][3] - s_G[j][3];
      float dist = sqrtf(dx*dx + dy*dy + dz*dz + dw*dw);
      float t = fmaxf(DELTA_DIS - dist, 0.f);
      lp = logf(t*t + 1.f);
    }
  }
  red[tid] = lp;
  __syncthreads();
  for (int s = 128; s > 0; s >>= 1) {
    if (tid < s) red[tid] += red[tid + s];
    __syncthreads();
  }
  if (tid == 0) {
    int nv = s_nv;
    float dis = 0.f;
    if (nv > 1) dis = 0.5f * red[0] / (float)(nv * (nv - 1));
    out[NB + n] = dis;
  }
}

// ---------------- pass 2: aggregation loss segment sums by text ----------------
__global__ __launch_bounds__(256) void pass2_kernel(
    const float* __restrict__ preds, const int* __restrict__ targets,
    float* __restrict__ ws) {
  const int n = blockIdx.y;
  const int tid = threadIdx.x;
  const int col = tid >> 1;

  const float4* __restrict__ c0 = (const float4*)(preds + ((size_t)n*6 + 2)*PPIX);
  const float4* __restrict__ c1 = (const float4*)(preds + ((size_t)n*6 + 3)*PPIX);
  const float4* __restrict__ c2 = (const float4*)(preds + ((size_t)n*6 + 4)*PPIX);
  const float4* __restrict__ c3 = (const float4*)(preds + ((size_t)n*6 + 5)*PPIX);
  const int4*  __restrict__ textv = (const int4*)(targets + (size_t)n*2*PPIX);

  __shared__ float4 s_G[MSEG];
  __shared__ float  s_l[MSEG][128];    // 8 KB
  if (tid < MSEG) s_G[tid] = ((const float4*)(ws + OFF_G + (size_t)n*MSEG*4))[tid];
  {
    float4* f4 = (float4*)&s_l[0][0];
#pragma unroll
    for (int i = 0; i < 2; ++i) f4[tid + i*256] = make_float4(0.f, 0.f, 0.f, 0.f);
  }
  __syncthreads();

#define PIX2(T, A0, A1, A2, A3) do {                            \
    int t_ = (T);                                               \
    float4 g = s_G[t_];                                         \
    float dx = (A0) - g.x, dy = (A1) - g.y;                     \
    float dz = (A2) - g.z, dw = (A3) - g.w;                     \
    float sq = fmaf(dx, dx, fmaf(dy, dy, fmaf(dz, dz, dw*dw))); \
    float dd = fmaxf(__fsqrt_rn(sq) - DELTA_AGG, 0.f);          \
    float l = __logf(fmaf(dd, dd, 1.f));                        \
    atomicAdd(&s_l[t_][col], l);                                \
  } while (0)

  const int base = blockIdx.x*1024 + tid;
#pragma unroll
  for (int it = 0; it < 4; ++it) {
    int p = base + it*256;
    int4 tt = textv[p];
    float4 a = c0[p], b = c1[p], c = c2[p], d = c3[p];
    PIX2(tt.x, a.x, b.x, c.x, d.x);
    PIX2(tt.y, a.y, b.y, c.y, d.y);
    PIX2(tt.z, a.z, b.z, c.z, d.z);
    PIX2(tt.w, a.w, b.w, c.w, d.w);
  }
#undef PIX2
  __syncthreads();

  if (tid < MSEG) {
    const float4* row = (const float4*)&s_l[tid][0];
    float s = 0.f;
#pragma unroll
    for (int i = 0; i < 32; ++i) {
      float4 v = row[i];
      s += (v.x + v.y) + (v.z + v.w);
    }
    atomicAdd(&ws[OFF_LSUM + n*MSEG + tid], s);
  }
}

// ---------------- finalize aggregation loss (one wave/batch) ----------------
__global__ __launch_bounds__(64) void finalize_agg_kernel(
    const float* __restrict__ ws, float* __restrict__ out) {
  const int n = blockIdx.x;
  const int tid = threadIdx.x;
  const float* cnt_k = ws + OFF_CNT_K + n*MSEG;
  const float* cnt_t = ws + OFF_CNT_T + n*MSEG;
  const float* lsum  = ws + OFF_LSUM  + n*MSEG;

  float lm = 0.f, vc = 0.f;
  if (tid >= 1 && tid < MSEG) {
    float ck = cnt_k[tid], ct = cnt_t[tid];
    if (ck > 0.f && ct > 0.f) {
      vc = 1.f;
      lm = lsum[tid] / fmaxf(ct, 1.f);
    }
  }
  for (int off = 32; off > 0; off >>= 1) {
    lm += __shfl_down(lm, off);
    vc += __shfl_down(vc, off);
  }
  if (tid == 0) {
    int nv = (int)(vc + 0.5f);
    out[n] = lm / (float)(nv > 1 ? nv : 1);
  }
}

extern "C" void kernel_launch(void* const* d_in, const int* in_sizes, int n_in,
                              void* d_out, int out_size, void* d_ws, size_t ws_size,
                              hipStream_t stream) {
  const float* preds   = (const float*)d_in[0];
  const int*   targets = (const int*)d_in[1];
  float* out = (float*)d_out;
  float* ws  = (float*)d_ws;

  hipMemsetAsync(d_ws, 0, WS_FLOATS * sizeof(float), stream);

  dim3 grid(GRIDX, NB);
  pass1_kernel<<<grid, 256, 0, stream>>>(preds, targets, ws);
  finalize_dis_kernel<<<NB, 256, 0, stream>>>(ws, out);
  pass2_kernel<<<grid, 256, 0, stream>>>(preds, targets, ws);
  finalize_agg_kernel<<<NB, 64, 0, stream>>>(ws, out);
}